// Round 6
// baseline (162.709 us; speedup 1.0000x reference)
//
#include <hip/hip_runtime.h>

// EndEffectorLoss R13: R12 single-wave structure, stage advance moved back
// into the per-lane global pointer (offset arg = 0).
//
// R12 post-mortem: absmax 13.3. The only unverified-HW-semantics change vs
// the passing R9/R11 was using global_load_lds's immediate-offset arg for the
// stage advance; for the FLAT-LDS path it is ambiguous whether that imm
// applies to the global vaddr or the LDS side. If LDS-side: stage 0 correct,
// stages 1-5 stage garbage -> O(10) absmax, exactly as observed. R13 reverts
// to per-stage pointer arithmetic (compile-time ST folds; backend may fold
// into the offset field itself, with correct semantics guaranteed).
//
// Kept from R12:
//  - 64-thread blocks: lanes 0-31 = 32 frames of pose A, lanes 32-63 = same
//    frames of pose B (per-lane DMA source addresses). Grid 2048, 18KB LDS
//    -> 8 blocks/CU candidate residency.
//  - A/B exchange via __shfl_xor(.,32): zero barriers.
//  - __launch_bounds__(64,2): VGPR cap 256.
//  - Grouped LDS reads (peak 5 live quads), end-site stages skip unused quads.
//  - Counted-vmcnt double-buffered DMA pipeline (T4): vmcnt(9) per stage,
//    drain to 0 only at the last stage.

struct V3 { float x, y, z; };
struct M3 { float m[3][3]; };   // row r = basis vector b_r (row-stacked)
struct FK { M3 o; V3 p; };

__device__ __forceinline__ V3 matvec(const M3& A, const V3& v) {
    return { A.m[0][0]*v.x + A.m[0][1]*v.y + A.m[0][2]*v.z,
             A.m[1][0]*v.x + A.m[1][1]*v.y + A.m[1][2]*v.z,
             A.m[2][0]*v.x + A.m[2][1]*v.y + A.m[2][2]*v.z };
}

__device__ __forceinline__ M3 matmul(const M3& A, const M3& B) {
    M3 C;
#pragma unroll
    for (int i = 0; i < 3; i++)
#pragma unroll
        for (int j = 0; j < 3; j++)
            C.m[i][j] = A.m[i][0]*B.m[0][j] + A.m[i][1]*B.m[1][j] + A.m[i][2]*B.m[2][j];
    return C;
}

// Gram-Schmidt from 6 scalars (matches jnp reference, f32).
__device__ __forceinline__ M3 rot6d(float v0, float v1, float v2,
                                    float v3, float v4, float v5) {
    float n1 = v0*v0 + v1*v1 + v2*v2;
    float r1 = 1.0f / sqrtf(n1);
    V3 b1 = { v0*r1, v1*r1, v2*r1 };
    float d = b1.x*v3 + b1.y*v4 + b1.z*v5;
    V3 u = { v3 - d*b1.x, v4 - d*b1.y, v5 - d*b1.z };
    float n2 = u.x*u.x + u.y*u.y + u.z*u.z;
    float r2 = 1.0f / sqrtf(n2);
    V3 b2 = { u.x*r2, u.y*r2, u.z*r2 };
    V3 b3 = { b1.y*b2.z - b1.z*b2.y, b1.z*b2.x - b1.x*b2.z, b1.x*b2.y - b1.y*b2.x };
    M3 R;
    R.m[0][0]=b1.x; R.m[0][1]=b1.y; R.m[0][2]=b1.z;
    R.m[1][0]=b2.x; R.m[1][1]=b2.y; R.m[1][2]=b2.z;
    R.m[2][0]=b3.x; R.m[2][1]=b3.y; R.m[2][2]=b3.z;
    return R;
}

__device__ __forceinline__ FK fk_step(float a0,float a1,float a2,float a3,float a4,float a5,
                                      float ox,float oy,float oz, const FK& par) {
    V3 t = matvec(par.o, {ox, oy, oz});
    FK s;
    s.p = { par.p.x + t.x, par.p.y + t.y, par.p.z + t.z };
    s.o = matmul(par.o, rot6d(a0, a1, a2, a3, a4, a5));
    return s;
}

__device__ __forceinline__ V3 fk_end(float ox, float oy, float oz, const FK& par) {
    V3 t = matvec(par.o, {ox, oy, oz});
    return { par.p.x + t.x, par.p.y + t.y, par.p.z + t.z };
}

// Async 16B global->LDS DMA: LDS dest wave-uniform (HW adds lane*16); global
// source is per-lane; offset arg ALWAYS 0 (semantics verified only for 0).
#define GLDS16(gp, lp) __builtin_amdgcn_global_load_lds( \
    (const __attribute__((address_space(1))) void*)(gp), \
    (__attribute__((address_space(3))) void*)(lp), 16, 0, 0)

// Counted waits; sched_barrier pins ordering (guide rule #18).
#define VWAIT(n) do { asm volatile("s_waitcnt vmcnt(" #n ")" ::: "memory"); \
                      __builtin_amdgcn_sched_barrier(0); } while (0)
#define LWAIT0()  do { asm volatile("s_waitcnt lgkmcnt(0)" ::: "memory"); \
                      __builtin_amdgcn_sched_barrier(0); } while (0)

// One FK stage = 9 DMA instrs (6 pose + 3 off). Stage advance in the POINTER:
// pose stride/stage = 24 floats, off = 12 floats (compile-time ST).
// Pose chunk mapping per half-wave: instr k, half-lane l5 -> global chunk
// idx = l5 + 32k -> frame f=idx/6, col c=idx%6. LDS slot = 64k + 32h + l5.
#define STAGE(B, ST) do { \
    GLDS16(psrc[0] + (ST)*24, &s_pose[B][  0]); \
    GLDS16(psrc[1] + (ST)*24, &s_pose[B][ 64]); \
    GLDS16(psrc[2] + (ST)*24, &s_pose[B][128]); \
    GLDS16(psrc[3] + (ST)*24, &s_pose[B][192]); \
    GLDS16(psrc[4] + (ST)*24, &s_pose[B][256]); \
    GLDS16(psrc[5] + (ST)*24, &s_pose[B][320]); \
    GLDS16(osrc[0] + (ST)*12, &s_off [B][  0]); \
    GLDS16(osrc[1] + (ST)*12, &s_off [B][ 64]); \
    GLDS16(osrc[2] + (ST)*12, &s_off [B][128]); \
} while (0)

// Reads, grouped by first/second joint pair of a stage.
#define RG1(B)  q0 = s_pose[B][ps[0]]; q1 = s_pose[B][ps[1]]; q2 = s_pose[B][ps[2]]; \
                r0 = s_off[B][os3[0]]; r1 = s_off[B][os3[1]];
#define RQ35(B) q3 = s_pose[B][ps[3]]; q4 = s_pose[B][ps[4]]; q5 = s_pose[B][ps[5]];
#define RQ34(B) q3 = s_pose[B][ps[3]]; q4 = s_pose[B][ps[4]];
#define RR2(B)  r2 = s_off[B][os3[2]];

// Joint jj in {0..3}: pose floats 6jj..6jj+5, off floats 3jj..3jj+2.
#define J0ROT  q0.x,q0.y,q0.z,q0.w,q1.x,q1.y
#define J1ROT  q1.z,q1.w,q2.x,q2.y,q2.z,q2.w
#define J2ROT  q3.x,q3.y,q3.z,q3.w,q4.x,q4.y
#define J3ROT  q4.z,q4.w,q5.x,q5.y,q5.z,q5.w
#define J0OFF  r0.x,r0.y,r0.z
#define J1OFF  r0.w,r1.x,r1.y
#define J2OFF  r1.z,r1.w,r2.x
#define J3OFF  r2.y,r2.z,r2.w

__global__ __launch_bounds__(64, 2)
void ee_loss_kernel(const float* __restrict__ poseA, const float* __restrict__ poseB,
                    const float* __restrict__ offA,  const float* __restrict__ offB,
                    const float* __restrict__ tA,    const float* __restrict__ tB,
                    float* __restrict__ out, float inv_count) {
    __shared__ float4 s_pose[2][384];   // 12.0 KB: [buf][64k + 32h + l5]
    __shared__ float4 s_off [2][192];   //  6.0 KB
    __shared__ float s_inv[6];
    __shared__ float s_d[15];

    const int lane = threadIdx.x;       // 0..63
    const int h    = lane >> 5;         // 0 = pose A half, 1 = pose B half
    const int l5   = lane & 31;         // frame-local 0..31
    const long long f0 = (long long)blockIdx.x * 32;

    const float* P = (h ? poseB : poseA) + f0 * 144;
    const float* O = (h ? offB  : offA ) + f0 * 72;

    // ---- t_pose constants (lanes 0..14; loads drain here, before any DMA) ----
    if (lane < 6) {
        const float* tp = (lane < 3) ? tA : tB;
        int ax = (lane < 3) ? lane : lane - 3;
        float mn = tp[ax], mx = mn;
#pragma unroll
        for (int j = 1; j < 24; j++) {
            float v = tp[j*3 + ax];
            mn = fminf(mn, v); mx = fmaxf(mx, v);
        }
        s_inv[lane] = 1.0f / (mx - mn);
    }
    if (lane < 15) {
        const int EE[5] = {10, 11, 15, 22, 23};
        int e = lane / 3, ax = lane - 3*e;
        int j = EE[e];
        float mnA = tA[ax], mxA = mnA, mnB = tB[ax], mxB = mnB;
#pragma unroll
        for (int k = 1; k < 24; k++) {
            float a = tA[k*3 + ax], b = tB[k*3 + ax];
            mnA = fminf(mnA, a); mxA = fmaxf(mxA, a);
            mnB = fminf(mnB, b); mxB = fmaxf(mxB, b);
        }
        s_d[lane] = tB[j*3 + ax]/(mxB - mnB) - tA[j*3 + ax]/(mxA - mnA);
    }
    __builtin_amdgcn_sched_barrier(0);  // t_pose loads must not sink past DMAs

    // Per-lane DMA source pointers (stage 0; stage advance = +ST*24 / +ST*12).
    const float* psrc[6];
#pragma unroll
    for (int k = 0; k < 6; k++) {
        int idx = l5 + 32*k, f = idx/6, c = idx - 6*f;
        psrc[k] = P + f*144 + c*4;
    }
    const float* osrc[3];
#pragma unroll
    for (int k = 0; k < 3; k++) {
        int idx = l5 + 32*k, f = idx/3, c = idx - 3*f;
        osrc[k] = O + f*72 + c*4;
    }

    // Per-lane LDS read slots (float4 units; stage-invariant).
    int ps[6], os3[3];
#pragma unroll
    for (int c = 0; c < 6; c++) {
        int idx = 6*l5 + c;
        ps[c] = ((idx >> 5) << 6) + (h << 5) + (idx & 31);
    }
#pragma unroll
    for (int c = 0; c < 3; c++) {
        int idx = 3*l5 + c;
        os3[c] = ((idx >> 5) << 6) + (h << 5) + (idx & 31);
    }

    // ---- prologue: 2 stages in flight ----
    STAGE(0, 0);
    STAGE(1, 1);

    float4 q0, q1, q2, q3, q4, q5, r0, r1, r2;

    // ---- stage 0 (joints 0..3) ----
    VWAIT(9);                           // st0 landed, st1 flying
    RG1(0); LWAIT0();
    FK s0; s0.o = rot6d(J0ROT); s0.p = { r0.x, r0.y, r0.z };
    FK s1 = fk_step(J1ROT, J1OFF, s0);
    RQ35(0); RR2(0); LWAIT0();          // all reads of buf0 done (WAR)
    STAGE(0, 2);
    FK s2 = fk_step(J2ROT, J2OFF, s0);
    FK s3 = fk_step(J3ROT, J3OFF, s0);

    // ---- stage 1 (joints 4..7) ----
    VWAIT(9);                           // st1 landed, st2 flying
    RG1(1); LWAIT0();
    FK s4 = fk_step(J0ROT, J0OFF, s1);
    FK s5 = fk_step(J1ROT, J1OFF, s2);
    RQ35(1); RR2(1); LWAIT0();
    STAGE(1, 3);
    FK s6 = fk_step(J2ROT, J2OFF, s3);
    FK s7 = fk_step(J3ROT, J3OFF, s4);

    // ---- stage 2 (joints 8..11; 10,11 end sites -> q3..q5 never read) ----
    VWAIT(9);                           // st2 landed, st3 flying
    RG1(0); LWAIT0();
    FK s8 = fk_step(J0ROT, J0OFF, s5);
    FK s9 = fk_step(J1ROT, J1OFF, s6);
    RR2(0); LWAIT0();
    STAGE(0, 4);
    V3 e10 = fk_end(J2OFF, s7);
    V3 e11 = fk_end(J3OFF, s8);

    // ---- stage 3 (joints 12..15; 15 end site -> q5 never read) ----
    VWAIT(9);                           // st3 landed, st4 flying
    RG1(1); LWAIT0();
    FK s12 = fk_step(J0ROT, J0OFF, s9);
    FK s13 = fk_step(J1ROT, J1OFF, s9);
    RQ34(1); RR2(1); LWAIT0();
    STAGE(1, 5);
    FK s14 = fk_step(J2ROT, J2OFF, s9);
    V3 e15 = fk_end(J3OFF, s12);

    // ---- stage 4 (joints 16..19) ----
    VWAIT(9);                           // st4 landed, st5 flying
    RG1(0); LWAIT0();
    FK s16 = fk_step(J0ROT, J0OFF, s13);
    FK s17 = fk_step(J1ROT, J1OFF, s14);
    RQ35(0); RR2(0); LWAIT0();
    FK s18 = fk_step(J2ROT, J2OFF, s16);
    FK s19 = fk_step(J3ROT, J3OFF, s17);

    // ---- stage 5 (joints 20..23; 22,23 end sites -> q3..q5 never read) ----
    VWAIT(0);                           // st5 landed (only drain-to-0 point)
    RG1(1); LWAIT0();
    FK s20 = fk_step(J0ROT, J0OFF, s18);
    FK s21 = fk_step(J1ROT, J1OFF, s19);
    RR2(1); LWAIT0();
    V3 e22 = fk_end(J2OFF, s20);
    V3 e23 = fk_end(J3OFF, s21);

    // ---- cross-half exchange: lane l <-> lane l^32 (A gets B's ee) ----
    float p0  = __shfl_xor(e10.x, 32, 64);
    float p1  = __shfl_xor(e10.y, 32, 64);
    float p2  = __shfl_xor(e10.z, 32, 64);
    float p3  = __shfl_xor(e11.x, 32, 64);
    float p4  = __shfl_xor(e11.y, 32, 64);
    float p5  = __shfl_xor(e11.z, 32, 64);
    float p6  = __shfl_xor(e15.x, 32, 64);
    float p7  = __shfl_xor(e15.y, 32, 64);
    float p8  = __shfl_xor(e15.z, 32, 64);
    float p9  = __shfl_xor(e22.x, 32, 64);
    float p10 = __shfl_xor(e22.y, 32, 64);
    float p11 = __shfl_xor(e22.z, 32, 64);
    float p12 = __shfl_xor(e23.x, 32, 64);
    float p13 = __shfl_xor(e23.y, 32, 64);
    float p14 = __shfl_xor(e23.z, 32, 64);

    float local = 0.0f;
    if (h == 0) {                       // A-half computes the loss terms
        const float iax = s_inv[0], iay = s_inv[1], iaz = s_inv[2];
        const float ibx = s_inv[3], iby = s_inv[4], ibz = s_inv[5];
        float t0  = e10.x*iax - p0 *ibx + s_d[ 0];
        float t1  = e10.y*iay - p1 *iby + s_d[ 1];
        float t2  = e10.z*iaz - p2 *ibz + s_d[ 2];
        float t3  = e11.x*iax - p3 *ibx + s_d[ 3];
        float t4  = e11.y*iay - p4 *iby + s_d[ 4];
        float t5  = e11.z*iaz - p5 *ibz + s_d[ 5];
        float t6  = e15.x*iax - p6 *ibx + s_d[ 6];
        float t7  = e15.y*iay - p7 *iby + s_d[ 7];
        float t8  = e15.z*iaz - p8 *ibz + s_d[ 8];
        float t9  = e22.x*iax - p9 *ibx + s_d[ 9];
        float t10 = e22.y*iay - p10*iby + s_d[10];
        float t11 = e22.z*iaz - p11*ibz + s_d[11];
        float t12 = e23.x*iax - p12*ibx + s_d[12];
        float t13 = e23.y*iay - p13*iby + s_d[13];
        float t14 = e23.z*iaz - p14*ibz + s_d[14];
        local = ((t0*t0 + t1*t1) + (t2*t2 + t3*t3) + (t4*t4 + t5*t5) +
                 (t6*t6 + t7*t7) + (t8*t8 + t9*t9) + (t10*t10 + t11*t11) +
                 (t12*t12 + t13*t13) + t14*t14) * inv_count;
    }
    // B-half contributes zeros; full-wave reduce then one atomic.
#pragma unroll
    for (int off = 32; off > 0; off >>= 1)
        local += __shfl_down(local, off, 64);
    if (lane == 0) atomicAdd(out, local);
}

extern "C" void kernel_launch(void* const* d_in, const int* in_sizes, int n_in,
                              void* d_out, int out_size, void* d_ws, size_t ws_size,
                              hipStream_t stream) {
    const float* poseA = (const float*)d_in[0];
    const float* poseB = (const float*)d_in[1];
    const float* offA  = (const float*)d_in[2];
    const float* offB  = (const float*)d_in[3];
    const float* tA    = (const float*)d_in[4];
    const float* tB    = (const float*)d_in[5];
    float* out = (float*)d_out;

    const int F = in_sizes[0] / 144;          // 65536
    const int blocks = F / 32;                // 2048 single-wave blocks
    const float inv_count = 1.0f / ((float)F * 15.0f);

    hipMemsetAsync(out, 0, sizeof(float), stream);
    ee_loss_kernel<<<blocks, 64, 0, stream>>>(poseA, poseB, offA, offB, tA, tB,
                                              out, inv_count);
}